// Round 3
// baseline (127.064 us; speedup 1.0000x reference)
//
#include <hip/hip_runtime.h>

#define L_LAYERS 783
#define L_PAD    784           // SEG * G_SEG
#define B_BATCH  8192
#define N_SITES  784
#define K_KRAUS  16
#define SEG      14
#define G_SEG    56            // 56 = 8 groups * 7 in combine

// ---------------------------------------------------------------------------
// Hermitian-reduced formulation.
// State v = (s00, s11, u, w), sigma = [[s00, u+iw], [u-iw, s11]].
// Per layer: v' = R v with R = A*xx0 + B*xx1 + C*xx3, xx = outer(x,x)/|x|^2.
// Since xx0 + xx3 = 1:  R = C + (A-C)*xx0 + B*xx1  -> 2 FMA per element.
// Tc layout per layer (48 floats): [0..15]=C, [16..31]=D=A-C, [32..47]=B.
// Layers l >= L_LAYERS are padded with R = I (C=I, D=0, B=0).
// ---------------------------------------------------------------------------
__device__ inline void t_elem(const float* __restrict__ krl, const float* __restrict__ kil,
                              int c, int d, int m, int q, float& tr, float& ti) {
    // T[cd][m][q] = sum_{k,a} K_k[2a+c][2*i1+i2] * conj(K_k[2a+d][2*j1+j2])
    int i1 = m >> 1, j1 = m & 1, i2 = q >> 1, j2 = q & 1;
    int p1 = 2 * i1 + i2, p2 = 2 * j1 + j2;
    float ar = 0.f, ai = 0.f;
    #pragma unroll 4
    for (int k = 0; k < K_KRAUS; ++k) {
        #pragma unroll
        for (int a = 0; a < 2; ++a) {
            int r1 = k * 16 + (2 * a + c) * 4 + p1;
            int r2 = k * 16 + (2 * a + d) * 4 + p2;
            float k1r = krl[r1], k1i = kil[r1];
            float k2r = krl[r2], k2i = kil[r2];
            ar += k1r * k2r + k1i * k2i;      // K1 * conj(K2)
            ai += k1i * k2r - k1r * k2i;
        }
    }
    tr = ar; ti = ai;
}

__global__ void build_T(const float* __restrict__ kr, const float* __restrict__ ki,
                        float* __restrict__ Tc) {
    int g = blockIdx.x * blockDim.x + threadIdx.x;
    if (g >= L_PAD * 16) return;
    int l  = g >> 4;
    int rc = g & 15;
    int row = rc >> 2, col = rc & 3;
    float* o = Tc + (size_t)l * 48;
    if (l >= L_LAYERS) {                       // identity pad layer
        o[rc]      = (row == col) ? 1.f : 0.f; // C = I
        o[16 + rc] = 0.f;                      // D = 0
        o[32 + rc] = 0.f;                      // B = 0
        return;
    }
    // rows: 0 -> Re s'00 (cd=0), 1 -> Re s'11 (cd=3), 2 -> Re s'01, 3 -> Im s'01 (cd=1)
    int cd = (row == 0) ? 0 : (row == 1) ? 3 : 1;
    int c = cd >> 1, d = cd & 1;
    const float* krl = kr + (size_t)l * (K_KRAUS * 16);
    const float* kil = ki + (size_t)l * (K_KRAUS * 16);

    // columns over sigma components: col0 <- s00 (m=0), col1 <- s11 (m=3),
    // col2 <- u (m=1 + m=2), col3 <- w (i*(m=1 - m=2))
    float Ur[4], Ui[4];
    for (int q = 0; q < 4; ++q) {
        float ur, ui;
        if (col == 0)      { t_elem(krl, kil, c, d, 0, q, ur, ui); }
        else if (col == 1) { t_elem(krl, kil, c, d, 3, q, ur, ui); }
        else {
            float t1r, t1i, t2r, t2i;
            t_elem(krl, kil, c, d, 1, q, t1r, t1i);
            t_elem(krl, kil, c, d, 2, q, t2r, t2i);
            if (col == 2) { ur = t1r + t2r; ui = t1i + t2i; }
            else          { ur = -(t1i - t2i); ui = t1r - t2r; }   // i*(T1-T2)
        }
        Ur[q] = ur; Ui[q] = ui;
    }
    // q=1,q=2 share xx1 -> combine.  A=coef(xx0), B=coef(xx1), C=coef(xx3)
    float A, Bc, Cc;
    if (row == 3) { A = Ui[0]; Bc = Ui[1] + Ui[2]; Cc = Ui[3]; }
    else          { A = Ur[0]; Bc = Ur[1] + Ur[2]; Cc = Ur[3]; }
    o[rc]      = Cc;
    o[16 + rc] = A - Cc;
    o[32 + rc] = Bc;
}

// ---------------------------------------------------------------------------
// Kernel 2: per (batch, segment) product of SEG real 4x4 transfer matrices.
// SEG is compile-time -> full unroll, X loads hoisted for ILP.
// P stored SoA: P[(s*16 + i) * B + b]  (coalesced stores & loads).
// ---------------------------------------------------------------------------
__global__ void __launch_bounds__(256)
seg_kernel(const float* __restrict__ X, const float* __restrict__ Tc,
           float* __restrict__ P) {
    __shared__ float tcs[SEG * 48];
    int s = blockIdx.y;
    int ls = s * SEG;
    for (int i = threadIdx.x; i < SEG * 48; i += 256) tcs[i] = Tc[(size_t)ls * 48 + i];
    __syncthreads();

    int b = blockIdx.x * 256 + threadIdx.x;
    const float* xp = X + (size_t)b * (N_SITES * 2);

    float pA[16], pB[16];
    #pragma unroll
    for (int i = 0; i < 16; ++i) pA[i] = (i % 5 == 0) ? 1.f : 0.f;

#define STEP(SRC, DST, I)                                                       \
    {                                                                           \
        int site = ls + (I) + 1;                                                \
        site = site > (N_SITES - 1) ? (N_SITES - 1) : site;                     \
        float x0 = xp[site * 2 + 0];                                            \
        float x1 = xp[site * 2 + 1];                                            \
        float inv = __builtin_amdgcn_rcpf(fmaf(x0, x0, x1 * x1));               \
        float xx0 = x0 * x0 * inv, xx1 = x0 * x1 * inv;                         \
        const float* tc = tcs + (I) * 48;                                       \
        float R[16];                                                            \
        _Pragma("unroll")                                                       \
        for (int e = 0; e < 16; ++e) R[e] = fmaf(tc[16 + e], xx0, tc[e]);       \
        _Pragma("unroll")                                                       \
        for (int e = 0; e < 16; ++e) R[e] = fmaf(tc[32 + e], xx1, R[e]);        \
        _Pragma("unroll")                                                       \
        for (int r = 0; r < 4; ++r) {                                           \
            _Pragma("unroll")                                                   \
            for (int cc = 0; cc < 4; ++cc)                                      \
                DST[r * 4 + cc] =                                               \
                    fmaf(R[r * 4 + 0], SRC[cc],                                 \
                    fmaf(R[r * 4 + 1], SRC[4 + cc],                             \
                    fmaf(R[r * 4 + 2], SRC[8 + cc],                             \
                         R[r * 4 + 3] * SRC[12 + cc])));                        \
        }                                                                       \
    }

    #pragma unroll
    for (int i = 0; i < SEG; i += 2) {       // SEG even -> result ends in pA
        STEP(pA, pB, i);
        STEP(pB, pA, i + 1);
    }
#undef STEP

    #pragma unroll
    for (int i = 0; i < 16; ++i)
        P[((size_t)(s * 16 + i)) * B_BATCH + b] = pA[i];
}

// ---------------------------------------------------------------------------
// Kernel 3: two-level combine. 8 threads per batch each multiply 7 segment
// matrices (coalesced SoA loads), exchange through LDS (pad 17, conflict-free),
// then lane<32 chains the 8 partials against the initial state.
// ---------------------------------------------------------------------------
__global__ void __launch_bounds__(256)
combine_kernel(const float* __restrict__ X, const float* __restrict__ P,
               float* __restrict__ out) {
    __shared__ float q[256][17];
    int t = threadIdx.x;
    int j = t >> 5, bl = t & 31;
    int b = blockIdx.x * 32 + bl;

    float qa[16], qb[16];
    #pragma unroll
    for (int i = 0; i < 16; ++i) qa[i] = (i % 5 == 0) ? 1.f : 0.f;

#define CSTEP(SRC, DST, K)                                                      \
    {                                                                           \
        float m[16];                                                            \
        _Pragma("unroll")                                                       \
        for (int i = 0; i < 16; ++i)                                            \
            m[i] = P[((size_t)((j * 7 + (K)) * 16 + i)) * B_BATCH + b];         \
        _Pragma("unroll")                                                       \
        for (int r = 0; r < 4; ++r) {                                           \
            _Pragma("unroll")                                                   \
            for (int cc = 0; cc < 4; ++cc)                                      \
                DST[r * 4 + cc] =                                               \
                    fmaf(m[r * 4 + 0], SRC[cc],                                 \
                    fmaf(m[r * 4 + 1], SRC[4 + cc],                             \
                    fmaf(m[r * 4 + 2], SRC[8 + cc],                             \
                         m[r * 4 + 3] * SRC[12 + cc])));                        \
        }                                                                       \
    }
    CSTEP(qa, qb, 0); CSTEP(qb, qa, 1);
    CSTEP(qa, qb, 2); CSTEP(qb, qa, 3);
    CSTEP(qa, qb, 4); CSTEP(qb, qa, 5);
    CSTEP(qa, qb, 6);                         // result in qb
#undef CSTEP

    #pragma unroll
    for (int i = 0; i < 16; ++i) q[t][i] = qb[i];
    __syncthreads();

    if (t < 32) {
        int b2 = blockIdx.x * 32 + t;
        const float* xp = X + (size_t)b2 * (N_SITES * 2);
        float x0 = xp[0], x1 = xp[1];
        float inv = __builtin_amdgcn_rcpf(fmaf(x0, x0, x1 * x1));
        float v0 = x0 * x0 * inv;   // s00
        float v1 = x1 * x1 * inv;   // s11
        float v2 = x0 * x1 * inv;   // u
        float v3 = 0.f;             // w
        #pragma unroll
        for (int jj = 0; jj < 8; ++jj) {
            const float* qq = q[jj * 32 + t];
            float n0 = fmaf(qq[0],  v0, fmaf(qq[1],  v1, fmaf(qq[2],  v2, qq[3]  * v3)));
            float n1 = fmaf(qq[4],  v0, fmaf(qq[5],  v1, fmaf(qq[6],  v2, qq[7]  * v3)));
            float n2 = fmaf(qq[8],  v0, fmaf(qq[9],  v1, fmaf(qq[10], v2, qq[11] * v3)));
            float n3 = fmaf(qq[12], v0, fmaf(qq[13], v1, fmaf(qq[14], v2, qq[15] * v3)));
            v0 = n0; v1 = n1; v2 = n2; v3 = n3;
        }
        out[b2] = v0;
    }
}

// ---------------------------------------------------------------------------
extern "C" void kernel_launch(void* const* d_in, const int* in_sizes, int n_in,
                              void* d_out, int out_size, void* d_ws, size_t ws_size,
                              hipStream_t stream) {
    const float* X  = (const float*)d_in[0];
    const float* kr = (const float*)d_in[1];
    const float* ki = (const float*)d_in[2];
    float* out = (float*)d_out;

    float* Tc = (float*)d_ws;
    size_t Tb = (size_t)L_PAD * 48 * sizeof(float);          // 150,528 B
    size_t Tb_al = (Tb + 255) & ~(size_t)255;
    float* P = (float*)((char*)d_ws + Tb_al);                // 56*16*8192*4 = 29.4 MB

    build_T<<<(L_PAD * 16 + 255) / 256, 256, 0, stream>>>(kr, ki, Tc);

    dim3 grid(B_BATCH / 256, G_SEG);
    seg_kernel<<<grid, 256, 0, stream>>>(X, Tc, P);

    combine_kernel<<<B_BATCH / 32, 256, 0, stream>>>(X, P, out);
}

// Round 4
// 82.640 us; speedup vs baseline: 1.5376x; 1.5376x over previous
//
#include <hip/hip_runtime.h>

#define L_LAYERS 783
#define L_PAD    784           // SEG * G_SEG
#define B_BATCH  8192
#define N_SITES  784
#define K_KRAUS  16
#define SEG      28
#define G_SEG    28
#define TPB      128           // seg_kernel: threads per block == batches per block

// ---------------------------------------------------------------------------
// Hermitian-reduced formulation.
// State v = (s00, s11, u, w), sigma = [[s00, u+iw], [u-iw, s11]].
// Per layer: v' = R v, R = C + D*xx0 + B*xx1 (D = A - C, since xx0+xx3 = 1),
// xx = outer(x,x)/|x|^2. Tc per layer: 48 floats = [C(16) | D(16) | B(16)],
// row-major 4x4 each -> float4-per-row friendly. Pad layer 783: R = I.
// ---------------------------------------------------------------------------
__device__ inline void t_elem(const float* __restrict__ krl, const float* __restrict__ kil,
                              int c, int d, int m, int q, float& tr, float& ti) {
    // T[cd][m][q] = sum_{k,a} K_k[2a+c][2*i1+i2] * conj(K_k[2a+d][2*j1+j2])
    int i1 = m >> 1, j1 = m & 1, i2 = q >> 1, j2 = q & 1;
    int p1 = 2 * i1 + i2, p2 = 2 * j1 + j2;
    float ar = 0.f, ai = 0.f;
    #pragma unroll 4
    for (int k = 0; k < K_KRAUS; ++k) {
        #pragma unroll
        for (int a = 0; a < 2; ++a) {
            int r1 = k * 16 + (2 * a + c) * 4 + p1;
            int r2 = k * 16 + (2 * a + d) * 4 + p2;
            float k1r = krl[r1], k1i = kil[r1];
            float k2r = krl[r2], k2i = kil[r2];
            ar += k1r * k2r + k1i * k2i;      // K1 * conj(K2)
            ai += k1i * k2r - k1r * k2i;
        }
    }
    tr = ar; ti = ai;
}

__global__ void build_T(const float* __restrict__ kr, const float* __restrict__ ki,
                        float* __restrict__ Tc) {
    int g = blockIdx.x * blockDim.x + threadIdx.x;
    if (g >= L_PAD * 16) return;
    int l  = g >> 4;
    int rc = g & 15;
    int row = rc >> 2, col = rc & 3;
    float* o = Tc + (size_t)l * 48;
    if (l >= L_LAYERS) {                       // identity pad layer
        o[rc]      = (row == col) ? 1.f : 0.f; // C = I
        o[16 + rc] = 0.f;                      // D = 0
        o[32 + rc] = 0.f;                      // B = 0
        return;
    }
    // rows: 0 -> Re s'00 (cd=0), 1 -> Re s'11 (cd=3), 2 -> Re s'01, 3 -> Im s'01 (cd=1)
    int cd = (row == 0) ? 0 : (row == 1) ? 3 : 1;
    int c = cd >> 1, d = cd & 1;
    const float* krl = kr + (size_t)l * (K_KRAUS * 16);
    const float* kil = ki + (size_t)l * (K_KRAUS * 16);

    // columns over sigma components: col0 <- s00 (m=0), col1 <- s11 (m=3),
    // col2 <- u (m=1 + m=2), col3 <- w (i*(m=1 - m=2))
    float Ur[4], Ui[4];
    for (int q = 0; q < 4; ++q) {
        float ur, ui;
        if (col == 0)      { t_elem(krl, kil, c, d, 0, q, ur, ui); }
        else if (col == 1) { t_elem(krl, kil, c, d, 3, q, ur, ui); }
        else {
            float t1r, t1i, t2r, t2i;
            t_elem(krl, kil, c, d, 1, q, t1r, t1i);
            t_elem(krl, kil, c, d, 2, q, t2r, t2i);
            if (col == 2) { ur = t1r + t2r; ui = t1i + t2i; }
            else          { ur = -(t1i - t2i); ui = t1r - t2r; }   // i*(T1-T2)
        }
        Ur[q] = ur; Ui[q] = ui;
    }
    float A, Bc, Cc;
    if (row == 3) { A = Ui[0]; Bc = Ui[1] + Ui[2]; Cc = Ui[3]; }
    else          { A = Ur[0]; Bc = Ur[1] + Ur[2]; Cc = Ur[3]; }
    o[rc]      = Cc;
    o[16 + rc] = A - Cc;
    o[32 + rc] = Bc;
}

// ---------------------------------------------------------------------------
// Kernel 2: per (batch-chunk, segment) product of SEG transfer matrices.
// X staged through LDS with a coalesced (site-run) mapping; xx computed on
// the fly. Tc staged as float4 (broadcast ds_read_b128 in compute phase).
// P stored SoA: P[(s*16 + i) * B + b]  (fully coalesced).
// ---------------------------------------------------------------------------
__global__ void __launch_bounds__(TPB)
seg_kernel(const float* __restrict__ X, const float* __restrict__ Tc,
           float* __restrict__ P) {
    __shared__ float4 tcs4[SEG * 12];          // 5376 B
    __shared__ float2 xxs[TPB][SEG + 1];       // 29696 B (pad -> stride 58 dwords)
    int t  = threadIdx.x;
    int s  = blockIdx.y;
    int ls = s * SEG;
    int b0 = blockIdx.x * TPB;

    // stage Tc (16 B granules, coalesced, tiny)
    const float4* tg = (const float4*)Tc + (size_t)ls * 12;
    #pragma unroll
    for (int i = t; i < SEG * 12; i += TPB) tcs4[i] = tg[i];

    // stage xx: linear idx walks sites fastest -> wave lanes cover contiguous
    // 224 B runs per batch row (coalesced-ish, each HBM line fetched once)
    const float2* Xp = (const float2*)X;
    for (int idx = t; idx < SEG * TPB; idx += TPB) {
        int col  = idx % SEG;                  // site offset within segment
        int row  = idx / SEG;                  // batch offset within block
        int site = ls + 1 + col;
        site = site < (N_SITES - 1) ? site : (N_SITES - 1);   // pad-layer clamp
        float2 xv = Xp[(size_t)(b0 + row) * N_SITES + site];
        float inv = __builtin_amdgcn_rcpf(fmaf(xv.x, xv.x, xv.y * xv.y));
        xxs[row][col] = make_float2(xv.x * xv.x * inv, xv.x * xv.y * inv);
    }
    __syncthreads();

    float pA[16], pB[16];
    #pragma unroll
    for (int i = 0; i < 16; ++i) pA[i] = (i % 5 == 0) ? 1.f : 0.f;

#define STEP(SRC, DST, I)                                                       \
    {                                                                           \
        float2 xx = xxs[t][I];                                                  \
        float R[16];                                                            \
        _Pragma("unroll")                                                       \
        for (int r = 0; r < 4; ++r) {                                           \
            float4 cv = tcs4[(I) * 12 + r];                                     \
            float4 dv = tcs4[(I) * 12 + 4 + r];                                 \
            float4 bv = tcs4[(I) * 12 + 8 + r];                                 \
            R[r * 4 + 0] = fmaf(bv.x, xx.y, fmaf(dv.x, xx.x, cv.x));            \
            R[r * 4 + 1] = fmaf(bv.y, xx.y, fmaf(dv.y, xx.x, cv.y));            \
            R[r * 4 + 2] = fmaf(bv.z, xx.y, fmaf(dv.z, xx.x, cv.z));            \
            R[r * 4 + 3] = fmaf(bv.w, xx.y, fmaf(dv.w, xx.x, cv.w));            \
        }                                                                       \
        _Pragma("unroll")                                                       \
        for (int r = 0; r < 4; ++r) {                                           \
            _Pragma("unroll")                                                   \
            for (int cc = 0; cc < 4; ++cc)                                      \
                DST[r * 4 + cc] =                                               \
                    fmaf(R[r * 4 + 0], SRC[cc],                                 \
                    fmaf(R[r * 4 + 1], SRC[4 + cc],                             \
                    fmaf(R[r * 4 + 2], SRC[8 + cc],                             \
                         R[r * 4 + 3] * SRC[12 + cc])));                        \
        }                                                                       \
    }

    #pragma unroll
    for (int i = 0; i < SEG; i += 2) {         // SEG even -> result ends in pA
        STEP(pA, pB, i);
        STEP(pB, pA, i + 1);
    }
#undef STEP

    int b = b0 + t;
    #pragma unroll
    for (int i = 0; i < 16; ++i)
        P[((size_t)(s * 16 + i)) * B_BATCH + b] = pA[i];
}

// ---------------------------------------------------------------------------
// Kernel 3: two-level combine. 4 threads per batch each chain 7 segment
// matrices (coalesced SoA loads), LDS exchange (stride 17, conflict-free),
// then 64 lanes chain the 4 partials against the initial state.
// ---------------------------------------------------------------------------
__global__ void __launch_bounds__(256)
combine_kernel(const float* __restrict__ X, const float* __restrict__ P,
               float* __restrict__ out) {
    __shared__ float q[256][17];
    int t  = threadIdx.x;
    int j  = t >> 6;                           // chain group 0..3
    int bl = t & 63;
    int b  = blockIdx.x * 64 + bl;

    float qa[16], qb[16];
    #pragma unroll
    for (int i = 0; i < 16; ++i) qa[i] = (i % 5 == 0) ? 1.f : 0.f;

#define CSTEP(SRC, DST, K)                                                      \
    {                                                                           \
        float m[16];                                                            \
        _Pragma("unroll")                                                       \
        for (int i = 0; i < 16; ++i)                                            \
            m[i] = P[((size_t)((j * 7 + (K)) * 16 + i)) * B_BATCH + b];         \
        _Pragma("unroll")                                                       \
        for (int r = 0; r < 4; ++r) {                                           \
            _Pragma("unroll")                                                   \
            for (int cc = 0; cc < 4; ++cc)                                      \
                DST[r * 4 + cc] =                                               \
                    fmaf(m[r * 4 + 0], SRC[cc],                                 \
                    fmaf(m[r * 4 + 1], SRC[4 + cc],                             \
                    fmaf(m[r * 4 + 2], SRC[8 + cc],                             \
                         m[r * 4 + 3] * SRC[12 + cc])));                        \
        }                                                                       \
    }
    CSTEP(qa, qb, 0); CSTEP(qb, qa, 1);
    CSTEP(qa, qb, 2); CSTEP(qb, qa, 3);
    CSTEP(qa, qb, 4); CSTEP(qb, qa, 5);
    CSTEP(qa, qb, 6);                          // 7 steps -> result in qb
#undef CSTEP

    #pragma unroll
    for (int i = 0; i < 16; ++i) q[t][i] = qb[i];
    __syncthreads();

    if (t < 64) {
        int b2 = blockIdx.x * 64 + t;
        const float2* Xp = (const float2*)X;
        float2 xv = Xp[(size_t)b2 * N_SITES];  // site 0
        float inv = __builtin_amdgcn_rcpf(fmaf(xv.x, xv.x, xv.y * xv.y));
        float v0 = xv.x * xv.x * inv;          // s00
        float v1 = xv.y * xv.y * inv;          // s11
        float v2 = xv.x * xv.y * inv;          // u
        float v3 = 0.f;                        // w
        #pragma unroll
        for (int jj = 0; jj < 4; ++jj) {
            const float* qq = q[jj * 64 + t];
            float n0 = fmaf(qq[0],  v0, fmaf(qq[1],  v1, fmaf(qq[2],  v2, qq[3]  * v3)));
            float n1 = fmaf(qq[4],  v0, fmaf(qq[5],  v1, fmaf(qq[6],  v2, qq[7]  * v3)));
            float n2 = fmaf(qq[8],  v0, fmaf(qq[9],  v1, fmaf(qq[10], v2, qq[11] * v3)));
            float n3 = fmaf(qq[12], v0, fmaf(qq[13], v1, fmaf(qq[14], v2, qq[15] * v3)));
            v0 = n0; v1 = n1; v2 = n2; v3 = n3;
        }
        out[b2] = v0;
    }
}

// ---------------------------------------------------------------------------
extern "C" void kernel_launch(void* const* d_in, const int* in_sizes, int n_in,
                              void* d_out, int out_size, void* d_ws, size_t ws_size,
                              hipStream_t stream) {
    const float* X  = (const float*)d_in[0];
    const float* kr = (const float*)d_in[1];
    const float* ki = (const float*)d_in[2];
    float* out = (float*)d_out;

    float* Tc = (float*)d_ws;
    size_t Tb = (size_t)L_PAD * 48 * sizeof(float);          // 150,528 B
    size_t Tb_al = (Tb + 255) & ~(size_t)255;
    float* P = (float*)((char*)d_ws + Tb_al);                // 28*16*8192*4 = 14.68 MB

    build_T<<<(L_PAD * 16 + 255) / 256, 256, 0, stream>>>(kr, ki, Tc);

    dim3 grid(B_BATCH / TPB, G_SEG);
    seg_kernel<<<grid, TPB, 0, stream>>>(X, Tc, P);

    combine_kernel<<<B_BATCH / 64, 256, 0, stream>>>(X, P, out);
}

// Round 5
// 77.284 us; speedup vs baseline: 1.6441x; 1.0693x over previous
//
#include <hip/hip_runtime.h>

#define L_LAYERS 783
#define L_PAD    784           // = SEGF*GF = SEGS*GS
#define B_BATCH  8192
#define N_SITES  784
#define K_KRAUS  16

// FAST path geometry
#define SEGF     14
#define GF       56
// FALLBACK geometry (round-4, proven within 15 MB workspace)
#define SEGS     28
#define GS       28
#define TPBS     128

// ---------------------------------------------------------------------------
// Hermitian-reduced formulation.
// State v = (s00, s11, u, w), sigma = [[s00, u+iw], [u-iw, s11]].
// Per layer: v' = R v, R = C + D*xx0 + B*xx1 (D = A - C, since xx0+xx3 = 1),
// xx = outer(x,x)/|x|^2. Tc per layer: 48 floats = [C(16) | D(16) | B(16)].
// Pad layers (l >= 783): R = I  (C=I, D=0, B=0) -> xx value irrelevant.
// ---------------------------------------------------------------------------
__device__ inline void t_elem(const float* __restrict__ krl, const float* __restrict__ kil,
                              int c, int d, int m, int q, float& tr, float& ti) {
    int i1 = m >> 1, j1 = m & 1, i2 = q >> 1, j2 = q & 1;
    int p1 = 2 * i1 + i2, p2 = 2 * j1 + j2;
    float ar = 0.f, ai = 0.f;
    #pragma unroll 4
    for (int k = 0; k < K_KRAUS; ++k) {
        #pragma unroll
        for (int a = 0; a < 2; ++a) {
            int r1 = k * 16 + (2 * a + c) * 4 + p1;
            int r2 = k * 16 + (2 * a + d) * 4 + p2;
            float k1r = krl[r1], k1i = kil[r1];
            float k2r = krl[r2], k2i = kil[r2];
            ar += k1r * k2r + k1i * k2i;      // K1 * conj(K2)
            ai += k1i * k2r - k1r * k2i;
        }
    }
    tr = ar; ti = ai;
}

__global__ void build_T(const float* __restrict__ kr, const float* __restrict__ ki,
                        float* __restrict__ Tc) {
    int g = blockIdx.x * blockDim.x + threadIdx.x;
    if (g >= L_PAD * 16) return;
    int l  = g >> 4;
    int rc = g & 15;
    int row = rc >> 2, col = rc & 3;
    float* o = Tc + (size_t)l * 48;
    if (l >= L_LAYERS) {                       // identity pad layer
        o[rc]      = (row == col) ? 1.f : 0.f;
        o[16 + rc] = 0.f;
        o[32 + rc] = 0.f;
        return;
    }
    int cd = (row == 0) ? 0 : (row == 1) ? 3 : 1;
    int c = cd >> 1, d = cd & 1;
    const float* krl = kr + (size_t)l * (K_KRAUS * 16);
    const float* kil = ki + (size_t)l * (K_KRAUS * 16);

    float Ur[4], Ui[4];
    for (int q = 0; q < 4; ++q) {
        float ur, ui;
        if (col == 0)      { t_elem(krl, kil, c, d, 0, q, ur, ui); }
        else if (col == 1) { t_elem(krl, kil, c, d, 3, q, ur, ui); }
        else {
            float t1r, t1i, t2r, t2i;
            t_elem(krl, kil, c, d, 1, q, t1r, t1i);
            t_elem(krl, kil, c, d, 2, q, t2r, t2i);
            if (col == 2) { ur = t1r + t2r; ui = t1i + t2i; }
            else          { ur = -(t1i - t2i); ui = t1r - t2r; }   // i*(T1-T2)
        }
        Ur[q] = ur; Ui[q] = ui;
    }
    float A, Bc, Cc;
    if (row == 3) { A = Ui[0]; Bc = Ui[1] + Ui[2]; Cc = Ui[3]; }
    else          { A = Ur[0]; Bc = Ur[1] + Ur[2]; Cc = Ur[3]; }
    o[rc]      = Cc;
    o[16 + rc] = A - Cc;
    o[32 + rc] = Bc;
}

// ---------------------------------------------------------------------------
// FAST kernel 1b: transpose + normalize-outer. XX[site][b] = (xx0, xx1).
// Tile 64 batches x 16 sites; both global phases fully coalesced.
// ---------------------------------------------------------------------------
__global__ void __launch_bounds__(256)
xx_kernel(const float* __restrict__ X, float2* __restrict__ XX) {
    __shared__ float2 ts[64][17];
    int t  = threadIdx.x;
    int b0 = blockIdx.x * 64;
    int s0 = blockIdx.y * 16;
    const float2* Xp = (const float2*)X;
    #pragma unroll
    for (int e = 0; e < 4; ++e) {
        int lin = t + e * 256;
        int bi = lin >> 4, si = lin & 15;
        float2 xv = Xp[(size_t)(b0 + bi) * N_SITES + (s0 + si)];
        float inv = __builtin_amdgcn_rcpf(fmaf(xv.x, xv.x, xv.y * xv.y));
        ts[bi][si] = make_float2(xv.x * xv.x * inv, xv.x * xv.y * inv);
    }
    __syncthreads();
    #pragma unroll
    for (int e = 0; e < 4; ++e) {
        int lin = t + e * 256;
        int si = lin >> 6, bi = lin & 63;
        XX[(size_t)(s0 + si) * B_BATCH + (b0 + bi)] = ts[bi][si];
    }
}

// ---------------------------------------------------------------------------
// FAST kernel 2: per (batch-chunk, segment) product of SEGF transfer matrices.
// xx loads straight from XX (coalesced dwordx2); LDS = Tc only (5.4 KB).
// P stored SoA: P[(s*16 + i) * B + b].
// ---------------------------------------------------------------------------
__global__ void __launch_bounds__(256, 4)
seg_fast(const float2* __restrict__ XX, const float* __restrict__ Tc,
         float* __restrict__ P) {
    __shared__ float4 tcs4[SEGF * 12];
    int t  = threadIdx.x;
    int s  = blockIdx.y;
    int ls = s * SEGF;
    const float4* tg = (const float4*)Tc + (size_t)ls * 12;
    for (int i = t; i < SEGF * 12; i += 256) tcs4[i] = tg[i];
    __syncthreads();

    int b = blockIdx.x * 256 + t;

    float pA[16], pB[16];
    #pragma unroll
    for (int i = 0; i < 16; ++i) pA[i] = (i % 5 == 0) ? 1.f : 0.f;

#define STEP(SRC, DST, I)                                                       \
    {                                                                           \
        int site = ls + 1 + (I);                                                \
        site = site < (N_SITES - 1) ? site : (N_SITES - 1);                     \
        float2 xx = XX[(size_t)site * B_BATCH + b];                             \
        float R[16];                                                            \
        _Pragma("unroll")                                                       \
        for (int r = 0; r < 4; ++r) {                                           \
            float4 cv = tcs4[(I) * 12 + r];                                     \
            float4 dv = tcs4[(I) * 12 + 4 + r];                                 \
            float4 bv = tcs4[(I) * 12 + 8 + r];                                 \
            R[r * 4 + 0] = fmaf(bv.x, xx.y, fmaf(dv.x, xx.x, cv.x));            \
            R[r * 4 + 1] = fmaf(bv.y, xx.y, fmaf(dv.y, xx.x, cv.y));            \
            R[r * 4 + 2] = fmaf(bv.z, xx.y, fmaf(dv.z, xx.x, cv.z));            \
            R[r * 4 + 3] = fmaf(bv.w, xx.y, fmaf(dv.w, xx.x, cv.w));            \
        }                                                                       \
        _Pragma("unroll")                                                       \
        for (int r = 0; r < 4; ++r) {                                           \
            _Pragma("unroll")                                                   \
            for (int cc = 0; cc < 4; ++cc)                                      \
                DST[r * 4 + cc] =                                               \
                    fmaf(R[r * 4 + 0], SRC[cc],                                 \
                    fmaf(R[r * 4 + 1], SRC[4 + cc],                             \
                    fmaf(R[r * 4 + 2], SRC[8 + cc],                             \
                         R[r * 4 + 3] * SRC[12 + cc])));                        \
        }                                                                       \
    }

    #pragma unroll
    for (int i = 0; i < SEGF; i += 2) {        // SEGF even -> ends in pA
        STEP(pA, pB, i);
        STEP(pB, pA, i + 1);
    }
#undef STEP

    #pragma unroll
    for (int i = 0; i < 16; ++i)
        P[((size_t)(s * 16 + i)) * B_BATCH + b] = pA[i];
}

// ---------------------------------------------------------------------------
// FAST kernel 3: two-level combine for G=56 (8 groups x 7-chain, then 8-chain).
// ---------------------------------------------------------------------------
__global__ void __launch_bounds__(256)
combine56(const float* __restrict__ X, const float* __restrict__ P,
          float* __restrict__ out) {
    __shared__ float q[256][17];
    int t = threadIdx.x;
    int j = t >> 5, bl = t & 31;
    int b = blockIdx.x * 32 + bl;

    float qa[16], qb[16];
    #pragma unroll
    for (int i = 0; i < 16; ++i) qa[i] = (i % 5 == 0) ? 1.f : 0.f;

#define CSTEP(SRC, DST, K)                                                      \
    {                                                                           \
        float m[16];                                                            \
        _Pragma("unroll")                                                       \
        for (int i = 0; i < 16; ++i)                                            \
            m[i] = P[((size_t)((j * 7 + (K)) * 16 + i)) * B_BATCH + b];         \
        _Pragma("unroll")                                                       \
        for (int r = 0; r < 4; ++r) {                                           \
            _Pragma("unroll")                                                   \
            for (int cc = 0; cc < 4; ++cc)                                      \
                DST[r * 4 + cc] =                                               \
                    fmaf(m[r * 4 + 0], SRC[cc],                                 \
                    fmaf(m[r * 4 + 1], SRC[4 + cc],                             \
                    fmaf(m[r * 4 + 2], SRC[8 + cc],                             \
                         m[r * 4 + 3] * SRC[12 + cc])));                        \
        }                                                                       \
    }
    CSTEP(qa, qb, 0); CSTEP(qb, qa, 1);
    CSTEP(qa, qb, 2); CSTEP(qb, qa, 3);
    CSTEP(qa, qb, 4); CSTEP(qb, qa, 5);
    CSTEP(qa, qb, 6);                          // result in qb
#undef CSTEP

    #pragma unroll
    for (int i = 0; i < 16; ++i) q[t][i] = qb[i];
    __syncthreads();

    if (t < 32) {
        int b2 = blockIdx.x * 32 + t;
        const float2* Xp = (const float2*)X;
        float2 xv = Xp[(size_t)b2 * N_SITES];
        float inv = __builtin_amdgcn_rcpf(fmaf(xv.x, xv.x, xv.y * xv.y));
        float v0 = xv.x * xv.x * inv;
        float v1 = xv.y * xv.y * inv;
        float v2 = xv.x * xv.y * inv;
        float v3 = 0.f;
        #pragma unroll
        for (int jj = 0; jj < 8; ++jj) {
            const float* qq = q[jj * 32 + t];
            float n0 = fmaf(qq[0],  v0, fmaf(qq[1],  v1, fmaf(qq[2],  v2, qq[3]  * v3)));
            float n1 = fmaf(qq[4],  v0, fmaf(qq[5],  v1, fmaf(qq[6],  v2, qq[7]  * v3)));
            float n2 = fmaf(qq[8],  v0, fmaf(qq[9],  v1, fmaf(qq[10], v2, qq[11] * v3)));
            float n3 = fmaf(qq[12], v0, fmaf(qq[13], v1, fmaf(qq[14], v2, qq[15] * v3)));
            v0 = n0; v1 = n1; v2 = n2; v3 = n3;
        }
        out[b2] = v0;
    }
}

// ---------------------------------------------------------------------------
// FALLBACK kernels (round-4, proven within 15 MB workspace)
// ---------------------------------------------------------------------------
__global__ void __launch_bounds__(TPBS)
seg_slow(const float* __restrict__ X, const float* __restrict__ Tc,
         float* __restrict__ P) {
    __shared__ float4 tcs4[SEGS * 12];
    __shared__ float2 xxs[TPBS][SEGS + 1];
    int t  = threadIdx.x;
    int s  = blockIdx.y;
    int ls = s * SEGS;
    int b0 = blockIdx.x * TPBS;

    const float4* tg = (const float4*)Tc + (size_t)ls * 12;
    #pragma unroll
    for (int i = t; i < SEGS * 12; i += TPBS) tcs4[i] = tg[i];

    const float2* Xp = (const float2*)X;
    for (int idx = t; idx < SEGS * TPBS; idx += TPBS) {
        int col  = idx % SEGS;
        int row  = idx / SEGS;
        int site = ls + 1 + col;
        site = site < (N_SITES - 1) ? site : (N_SITES - 1);
        float2 xv = Xp[(size_t)(b0 + row) * N_SITES + site];
        float inv = __builtin_amdgcn_rcpf(fmaf(xv.x, xv.x, xv.y * xv.y));
        xxs[row][col] = make_float2(xv.x * xv.x * inv, xv.x * xv.y * inv);
    }
    __syncthreads();

    float pA[16], pB[16];
    #pragma unroll
    for (int i = 0; i < 16; ++i) pA[i] = (i % 5 == 0) ? 1.f : 0.f;

#define STEP(SRC, DST, I)                                                       \
    {                                                                           \
        float2 xx = xxs[t][I];                                                  \
        float R[16];                                                            \
        _Pragma("unroll")                                                       \
        for (int r = 0; r < 4; ++r) {                                           \
            float4 cv = tcs4[(I) * 12 + r];                                     \
            float4 dv = tcs4[(I) * 12 + 4 + r];                                 \
            float4 bv = tcs4[(I) * 12 + 8 + r];                                 \
            R[r * 4 + 0] = fmaf(bv.x, xx.y, fmaf(dv.x, xx.x, cv.x));            \
            R[r * 4 + 1] = fmaf(bv.y, xx.y, fmaf(dv.y, xx.x, cv.y));            \
            R[r * 4 + 2] = fmaf(bv.z, xx.y, fmaf(dv.z, xx.x, cv.z));            \
            R[r * 4 + 3] = fmaf(bv.w, xx.y, fmaf(dv.w, xx.x, cv.w));            \
        }                                                                       \
        _Pragma("unroll")                                                       \
        for (int r = 0; r < 4; ++r) {                                           \
            _Pragma("unroll")                                                   \
            for (int cc = 0; cc < 4; ++cc)                                      \
                DST[r * 4 + cc] =                                               \
                    fmaf(R[r * 4 + 0], SRC[cc],                                 \
                    fmaf(R[r * 4 + 1], SRC[4 + cc],                             \
                    fmaf(R[r * 4 + 2], SRC[8 + cc],                             \
                         R[r * 4 + 3] * SRC[12 + cc])));                        \
        }                                                                       \
    }

    #pragma unroll
    for (int i = 0; i < SEGS; i += 2) {
        STEP(pA, pB, i);
        STEP(pB, pA, i + 1);
    }
#undef STEP

    int b = b0 + t;
    #pragma unroll
    for (int i = 0; i < 16; ++i)
        P[((size_t)(s * 16 + i)) * B_BATCH + b] = pA[i];
}

__global__ void __launch_bounds__(256)
combine28(const float* __restrict__ X, const float* __restrict__ P,
          float* __restrict__ out) {
    __shared__ float q[256][17];
    int t  = threadIdx.x;
    int j  = t >> 6;
    int bl = t & 63;
    int b  = blockIdx.x * 64 + bl;

    float qa[16], qb[16];
    #pragma unroll
    for (int i = 0; i < 16; ++i) qa[i] = (i % 5 == 0) ? 1.f : 0.f;

#define CSTEP(SRC, DST, K)                                                      \
    {                                                                           \
        float m[16];                                                            \
        _Pragma("unroll")                                                       \
        for (int i = 0; i < 16; ++i)                                            \
            m[i] = P[((size_t)((j * 7 + (K)) * 16 + i)) * B_BATCH + b];         \
        _Pragma("unroll")                                                       \
        for (int r = 0; r < 4; ++r) {                                           \
            _Pragma("unroll")                                                   \
            for (int cc = 0; cc < 4; ++cc)                                      \
                DST[r * 4 + cc] =                                               \
                    fmaf(m[r * 4 + 0], SRC[cc],                                 \
                    fmaf(m[r * 4 + 1], SRC[4 + cc],                             \
                    fmaf(m[r * 4 + 2], SRC[8 + cc],                             \
                         m[r * 4 + 3] * SRC[12 + cc])));                        \
        }                                                                       \
    }
    CSTEP(qa, qb, 0); CSTEP(qb, qa, 1);
    CSTEP(qa, qb, 2); CSTEP(qb, qa, 3);
    CSTEP(qa, qb, 4); CSTEP(qb, qa, 5);
    CSTEP(qa, qb, 6);
#undef CSTEP

    #pragma unroll
    for (int i = 0; i < 16; ++i) q[t][i] = qb[i];
    __syncthreads();

    if (t < 64) {
        int b2 = blockIdx.x * 64 + t;
        const float2* Xp = (const float2*)X;
        float2 xv = Xp[(size_t)b2 * N_SITES];
        float inv = __builtin_amdgcn_rcpf(fmaf(xv.x, xv.x, xv.y * xv.y));
        float v0 = xv.x * xv.x * inv;
        float v1 = xv.y * xv.y * inv;
        float v2 = xv.x * xv.y * inv;
        float v3 = 0.f;
        #pragma unroll
        for (int jj = 0; jj < 4; ++jj) {
            const float* qq = q[jj * 64 + t];
            float n0 = fmaf(qq[0],  v0, fmaf(qq[1],  v1, fmaf(qq[2],  v2, qq[3]  * v3)));
            float n1 = fmaf(qq[4],  v0, fmaf(qq[5],  v1, fmaf(qq[6],  v2, qq[7]  * v3)));
            float n2 = fmaf(qq[8],  v0, fmaf(qq[9],  v1, fmaf(qq[10], v2, qq[11] * v3)));
            float n3 = fmaf(qq[12], v0, fmaf(qq[13], v1, fmaf(qq[14], v2, qq[15] * v3)));
            v0 = n0; v1 = n1; v2 = n2; v3 = n3;
        }
        out[b2] = v0;
    }
}

// ---------------------------------------------------------------------------
extern "C" void kernel_launch(void* const* d_in, const int* in_sizes, int n_in,
                              void* d_out, int out_size, void* d_ws, size_t ws_size,
                              hipStream_t stream) {
    const float* X  = (const float*)d_in[0];
    const float* kr = (const float*)d_in[1];
    const float* ki = (const float*)d_in[2];
    float* out = (float*)d_out;

    float* Tc = (float*)d_ws;
    const size_t Tb  = (size_t)L_PAD * 48 * sizeof(float);         // 150,528 (256-mult)
    const size_t XXb = (size_t)N_SITES * B_BATCH * sizeof(float2); // 51,380,224
    const size_t Pfb = (size_t)GF * 16 * B_BATCH * sizeof(float);  // 29,360,128

    build_T<<<(L_PAD * 16 + 255) / 256, 256, 0, stream>>>(kr, ki, Tc);

    if (ws_size >= Tb + XXb + Pfb) {
        // FAST path
        float2* XX = (float2*)((char*)d_ws + Tb);
        float*  P  = (float*)((char*)d_ws + Tb + XXb);

        dim3 gx(B_BATCH / 64, N_SITES / 16);
        xx_kernel<<<gx, 256, 0, stream>>>(X, XX);

        dim3 gs(B_BATCH / 256, GF);
        seg_fast<<<gs, 256, 0, stream>>>(XX, Tc, P);

        combine56<<<B_BATCH / 32, 256, 0, stream>>>(X, P, out);
    } else {
        // FALLBACK (round-4 path, 14.8 MB)
        float* P = (float*)((char*)d_ws + Tb);
        dim3 gs(B_BATCH / TPBS, GS);
        seg_slow<<<gs, TPBS, 0, stream>>>(X, Tc, P);
        combine28<<<B_BATCH / 64, 256, 0, stream>>>(X, P, out);
    }
}

// Round 6
// 51.916 us; speedup vs baseline: 2.4475x; 1.4886x over previous
//
#include <hip/hip_runtime.h>

#define L_LAYERS 783
#define L_PAD    784           // = SEGF*GF = SEGS*GS
#define B_BATCH  8192
#define N_SITES  784
#define K_KRAUS  16

// FAST path geometry
#define SEGF     14
#define GF       56
// FALLBACK geometry (round-4, proven within 15 MB workspace)
#define SEGS     28
#define GS       28
#define TPBS     128

// ---------------------------------------------------------------------------
// Hermitian-reduced formulation.
// State v = (s00, s11, u, w), sigma = [[s00, u+iw], [u-iw, s11]].
// Per layer: v' = R v, R = C + D*xx0 + B*xx1 (D = A - C, since xx0+xx3 = 1),
// xx = outer(x,x)/|x|^2. Tc per layer: 48 floats = [C(16) | D(16) | B(16)].
// Pad layers (l >= 783): R = I  (C=I, D=0, B=0).
//
// build_T: one block per layer. Kraus layer (256 complex) staged in LDS.
// Phase 1: 192 threads compute 48 Gram entries G[ci][m][q] (ci: 0=(c0,d0),
// 1=(c0,d1), 2=(c1,d1)), 4-way split over k, shfl_xor reduce in 4-lane groups.
// Phase 2: 16 threads assemble the 48 Tc floats.
// ---------------------------------------------------------------------------
__global__ void __launch_bounds__(256)
build_T(const float* __restrict__ kr, const float* __restrict__ ki,
        float* __restrict__ Tc) {
    __shared__ float lr[K_KRAUS * 16];
    __shared__ float li[K_KRAUS * 16];
    __shared__ float gr[48], gi[48];
    int l = blockIdx.x;
    int t = threadIdx.x;
    float* o = Tc + (size_t)l * 48;

    if (l >= L_LAYERS) {                        // identity pad layer
        if (t < 16) {
            int row = t >> 2, col = t & 3;
            o[t]      = (row == col) ? 1.f : 0.f;
            o[16 + t] = 0.f;
            o[32 + t] = 0.f;
        }
        return;
    }

    lr[t] = kr[(size_t)l * 256 + t];
    li[t] = ki[(size_t)l * 256 + t];
    __syncthreads();

    if (t < 192) {
        int e = t >> 2, chunk = t & 3;
        int ci = e >> 4;                        // 0,1,2
        int c = ci >> 1, d = (ci + 1) >> 1;     // (0,0),(0,1),(1,1)
        int m = (e >> 2) & 3, q = e & 3;
        int i1 = m >> 1, j1 = m & 1, i2 = q >> 1, j2 = q & 1;
        int off1 = c * 4 + 2 * i1 + i2;
        int off2 = d * 4 + 2 * j1 + j2;
        float ar = 0.f, ai = 0.f;
        #pragma unroll
        for (int kk = 0; kk < 4; ++kk) {
            int kbase = (chunk * 4 + kk) * 16;
            #pragma unroll
            for (int a = 0; a < 2; ++a) {
                int x1 = kbase + a * 8 + off1;
                int x2 = kbase + a * 8 + off2;
                float k1r = lr[x1], k1i = li[x1];
                float k2r = lr[x2], k2i = li[x2];
                ar += k1r * k2r + k1i * k2i;    // K1 * conj(K2)
                ai += k1i * k2r - k1r * k2i;
            }
        }
        ar += __shfl_xor(ar, 1); ar += __shfl_xor(ar, 2);
        ai += __shfl_xor(ai, 1); ai += __shfl_xor(ai, 2);
        if (chunk == 0) { gr[e] = ar; gi[e] = ai; }
    }
    __syncthreads();

    if (t < 16) {
        int row = t >> 2, col = t & 3;
        int ci = (row == 0) ? 0 : (row == 1) ? 2 : 1;
        int base = ci * 16;
        float Ur[4], Ui[4];
        #pragma unroll
        for (int q = 0; q < 4; ++q) {
            if (col == 0)      { Ur[q] = gr[base + q];      Ui[q] = gi[base + q]; }
            else if (col == 1) { Ur[q] = gr[base + 12 + q]; Ui[q] = gi[base + 12 + q]; }
            else {
                float t1r = gr[base + 4 + q], t1i = gi[base + 4 + q];
                float t2r = gr[base + 8 + q], t2i = gi[base + 8 + q];
                if (col == 2) { Ur[q] = t1r + t2r;    Ui[q] = t1i + t2i; }
                else          { Ur[q] = -(t1i - t2i); Ui[q] = t1r - t2r; }   // i*(T1-T2)
            }
        }
        float A, Bc, Cc;
        if (row == 3) { A = Ui[0]; Bc = Ui[1] + Ui[2]; Cc = Ui[3]; }
        else          { A = Ur[0]; Bc = Ur[1] + Ur[2]; Cc = Ur[3]; }
        o[t]      = Cc;
        o[16 + t] = A - Cc;
        o[32 + t] = Bc;
    }
}

// ---------------------------------------------------------------------------
// FAST kernel 1b: transpose + normalize-outer. XX[site][b] = (xx0, xx1).
// ---------------------------------------------------------------------------
__global__ void __launch_bounds__(256)
xx_kernel(const float* __restrict__ X, float2* __restrict__ XX) {
    __shared__ float2 ts[64][17];
    int t  = threadIdx.x;
    int b0 = blockIdx.x * 64;
    int s0 = blockIdx.y * 16;
    const float2* Xp = (const float2*)X;
    #pragma unroll
    for (int e = 0; e < 4; ++e) {
        int lin = t + e * 256;
        int bi = lin >> 4, si = lin & 15;
        float2 xv = Xp[(size_t)(b0 + bi) * N_SITES + (s0 + si)];
        float inv = __builtin_amdgcn_rcpf(fmaf(xv.x, xv.x, xv.y * xv.y));
        ts[bi][si] = make_float2(xv.x * xv.x * inv, xv.x * xv.y * inv);
    }
    __syncthreads();
    #pragma unroll
    for (int e = 0; e < 4; ++e) {
        int lin = t + e * 256;
        int si = lin >> 6, bi = lin & 63;
        XX[(size_t)(s0 + si) * B_BATCH + (b0 + bi)] = ts[bi][si];
    }
}

// ---------------------------------------------------------------------------
// FAST kernel 2: per (batch-chunk, segment) product of SEGF transfer matrices.
// ---------------------------------------------------------------------------
__global__ void __launch_bounds__(256, 4)
seg_fast(const float2* __restrict__ XX, const float* __restrict__ Tc,
         float* __restrict__ P) {
    __shared__ float4 tcs4[SEGF * 12];
    int t  = threadIdx.x;
    int s  = blockIdx.y;
    int ls = s * SEGF;
    const float4* tg = (const float4*)Tc + (size_t)ls * 12;
    for (int i = t; i < SEGF * 12; i += 256) tcs4[i] = tg[i];
    __syncthreads();

    int b = blockIdx.x * 256 + t;

    float pA[16], pB[16];
    #pragma unroll
    for (int i = 0; i < 16; ++i) pA[i] = (i % 5 == 0) ? 1.f : 0.f;

#define STEP(SRC, DST, I)                                                       \
    {                                                                           \
        int site = ls + 1 + (I);                                                \
        site = site < (N_SITES - 1) ? site : (N_SITES - 1);                     \
        float2 xx = XX[(size_t)site * B_BATCH + b];                             \
        float R[16];                                                            \
        _Pragma("unroll")                                                       \
        for (int r = 0; r < 4; ++r) {                                           \
            float4 cv = tcs4[(I) * 12 + r];                                     \
            float4 dv = tcs4[(I) * 12 + 4 + r];                                 \
            float4 bv = tcs4[(I) * 12 + 8 + r];                                 \
            R[r * 4 + 0] = fmaf(bv.x, xx.y, fmaf(dv.x, xx.x, cv.x));            \
            R[r * 4 + 1] = fmaf(bv.y, xx.y, fmaf(dv.y, xx.x, cv.y));            \
            R[r * 4 + 2] = fmaf(bv.z, xx.y, fmaf(dv.z, xx.x, cv.z));            \
            R[r * 4 + 3] = fmaf(bv.w, xx.y, fmaf(dv.w, xx.x, cv.w));            \
        }                                                                       \
        _Pragma("unroll")                                                       \
        for (int r = 0; r < 4; ++r) {                                           \
            _Pragma("unroll")                                                   \
            for (int cc = 0; cc < 4; ++cc)                                      \
                DST[r * 4 + cc] =                                               \
                    fmaf(R[r * 4 + 0], SRC[cc],                                 \
                    fmaf(R[r * 4 + 1], SRC[4 + cc],                             \
                    fmaf(R[r * 4 + 2], SRC[8 + cc],                             \
                         R[r * 4 + 3] * SRC[12 + cc])));                        \
        }                                                                       \
    }

    #pragma unroll
    for (int i = 0; i < SEGF; i += 2) {        // SEGF even -> ends in pA
        STEP(pA, pB, i);
        STEP(pB, pA, i + 1);
    }
#undef STEP

    #pragma unroll
    for (int i = 0; i < 16; ++i)
        P[((size_t)(s * 16 + i)) * B_BATCH + b] = pA[i];
}

// ---------------------------------------------------------------------------
// FAST kernel 3: two-level combine for G=56 (8 groups x 7-chain, then 8-chain).
// ---------------------------------------------------------------------------
__global__ void __launch_bounds__(256)
combine56(const float* __restrict__ X, const float* __restrict__ P,
          float* __restrict__ out) {
    __shared__ float q[256][17];
    int t = threadIdx.x;
    int j = t >> 5, bl = t & 31;
    int b = blockIdx.x * 32 + bl;

    float qa[16], qb[16];
    #pragma unroll
    for (int i = 0; i < 16; ++i) qa[i] = (i % 5 == 0) ? 1.f : 0.f;

#define CSTEP(SRC, DST, K)                                                      \
    {                                                                           \
        float m[16];                                                            \
        _Pragma("unroll")                                                       \
        for (int i = 0; i < 16; ++i)                                            \
            m[i] = P[((size_t)((j * 7 + (K)) * 16 + i)) * B_BATCH + b];         \
        _Pragma("unroll")                                                       \
        for (int r = 0; r < 4; ++r) {                                           \
            _Pragma("unroll")                                                   \
            for (int cc = 0; cc < 4; ++cc)                                      \
                DST[r * 4 + cc] =                                               \
                    fmaf(m[r * 4 + 0], SRC[cc],                                 \
                    fmaf(m[r * 4 + 1], SRC[4 + cc],                             \
                    fmaf(m[r * 4 + 2], SRC[8 + cc],                             \
                         m[r * 4 + 3] * SRC[12 + cc])));                        \
        }                                                                       \
    }
    CSTEP(qa, qb, 0); CSTEP(qb, qa, 1);
    CSTEP(qa, qb, 2); CSTEP(qb, qa, 3);
    CSTEP(qa, qb, 4); CSTEP(qb, qa, 5);
    CSTEP(qa, qb, 6);                          // result in qb
#undef CSTEP

    #pragma unroll
    for (int i = 0; i < 16; ++i) q[t][i] = qb[i];
    __syncthreads();

    if (t < 32) {
        int b2 = blockIdx.x * 32 + t;
        const float2* Xp = (const float2*)X;
        float2 xv = Xp[(size_t)b2 * N_SITES];
        float inv = __builtin_amdgcn_rcpf(fmaf(xv.x, xv.x, xv.y * xv.y));
        float v0 = xv.x * xv.x * inv;
        float v1 = xv.y * xv.y * inv;
        float v2 = xv.x * xv.y * inv;
        float v3 = 0.f;
        #pragma unroll
        for (int jj = 0; jj < 8; ++jj) {
            const float* qq = q[jj * 32 + t];
            float n0 = fmaf(qq[0],  v0, fmaf(qq[1],  v1, fmaf(qq[2],  v2, qq[3]  * v3)));
            float n1 = fmaf(qq[4],  v0, fmaf(qq[5],  v1, fmaf(qq[6],  v2, qq[7]  * v3)));
            float n2 = fmaf(qq[8],  v0, fmaf(qq[9],  v1, fmaf(qq[10], v2, qq[11] * v3)));
            float n3 = fmaf(qq[12], v0, fmaf(qq[13], v1, fmaf(qq[14], v2, qq[15] * v3)));
            v0 = n0; v1 = n1; v2 = n2; v3 = n3;
        }
        out[b2] = v0;
    }
}

// ---------------------------------------------------------------------------
// FALLBACK kernels (round-4 path, proven within 15 MB workspace)
// ---------------------------------------------------------------------------
__global__ void __launch_bounds__(TPBS)
seg_slow(const float* __restrict__ X, const float* __restrict__ Tc,
         float* __restrict__ P) {
    __shared__ float4 tcs4[SEGS * 12];
    __shared__ float2 xxs[TPBS][SEGS + 1];
    int t  = threadIdx.x;
    int s  = blockIdx.y;
    int ls = s * SEGS;
    int b0 = blockIdx.x * TPBS;

    const float4* tg = (const float4*)Tc + (size_t)ls * 12;
    #pragma unroll
    for (int i = t; i < SEGS * 12; i += TPBS) tcs4[i] = tg[i];

    const float2* Xp = (const float2*)X;
    for (int idx = t; idx < SEGS * TPBS; idx += TPBS) {
        int col  = idx % SEGS;
        int row  = idx / SEGS;
        int site = ls + 1 + col;
        site = site < (N_SITES - 1) ? site : (N_SITES - 1);
        float2 xv = Xp[(size_t)(b0 + row) * N_SITES + site];
        float inv = __builtin_amdgcn_rcpf(fmaf(xv.x, xv.x, xv.y * xv.y));
        xxs[row][col] = make_float2(xv.x * xv.x * inv, xv.x * xv.y * inv);
    }
    __syncthreads();

    float pA[16], pB[16];
    #pragma unroll
    for (int i = 0; i < 16; ++i) pA[i] = (i % 5 == 0) ? 1.f : 0.f;

#define STEP(SRC, DST, I)                                                       \
    {                                                                           \
        float2 xx = xxs[t][I];                                                  \
        float R[16];                                                            \
        _Pragma("unroll")                                                       \
        for (int r = 0; r < 4; ++r) {                                           \
            float4 cv = tcs4[(I) * 12 + r];                                     \
            float4 dv = tcs4[(I) * 12 + 4 + r];                                 \
            float4 bv = tcs4[(I) * 12 + 8 + r];                                 \
            R[r * 4 + 0] = fmaf(bv.x, xx.y, fmaf(dv.x, xx.x, cv.x));            \
            R[r * 4 + 1] = fmaf(bv.y, xx.y, fmaf(dv.y, xx.x, cv.y));            \
            R[r * 4 + 2] = fmaf(bv.z, xx.y, fmaf(dv.z, xx.x, cv.z));            \
            R[r * 4 + 3] = fmaf(bv.w, xx.y, fmaf(dv.w, xx.x, cv.w));            \
        }                                                                       \
        _Pragma("unroll")                                                       \
        for (int r = 0; r < 4; ++r) {                                           \
            _Pragma("unroll")                                                   \
            for (int cc = 0; cc < 4; ++cc)                                      \
                DST[r * 4 + cc] =                                               \
                    fmaf(R[r * 4 + 0], SRC[cc],                                 \
                    fmaf(R[r * 4 + 1], SRC[4 + cc],                             \
                    fmaf(R[r * 4 + 2], SRC[8 + cc],                             \
                         R[r * 4 + 3] * SRC[12 + cc])));                        \
        }                                                                       \
    }

    #pragma unroll
    for (int i = 0; i < SEGS; i += 2) {
        STEP(pA, pB, i);
        STEP(pB, pA, i + 1);
    }
#undef STEP

    int b = b0 + t;
    #pragma unroll
    for (int i = 0; i < 16; ++i)
        P[((size_t)(s * 16 + i)) * B_BATCH + b] = pA[i];
}

__global__ void __launch_bounds__(256)
combine28(const float* __restrict__ X, const float* __restrict__ P,
          float* __restrict__ out) {
    __shared__ float q[256][17];
    int t  = threadIdx.x;
    int j  = t >> 6;
    int bl = t & 63;
    int b  = blockIdx.x * 64 + bl;

    float qa[16], qb[16];
    #pragma unroll
    for (int i = 0; i < 16; ++i) qa[i] = (i % 5 == 0) ? 1.f : 0.f;

#define CSTEP(SRC, DST, K)                                                      \
    {                                                                           \
        float m[16];                                                            \
        _Pragma("unroll")                                                       \
        for (int i = 0; i < 16; ++i)                                            \
            m[i] = P[((size_t)((j * 7 + (K)) * 16 + i)) * B_BATCH + b];         \
        _Pragma("unroll")                                                       \
        for (int r = 0; r < 4; ++r) {                                           \
            _Pragma("unroll")                                                   \
            for (int cc = 0; cc < 4; ++cc)                                      \
                DST[r * 4 + cc] =                                               \
                    fmaf(m[r * 4 + 0], SRC[cc],                                 \
                    fmaf(m[r * 4 + 1], SRC[4 + cc],                             \
                    fmaf(m[r * 4 + 2], SRC[8 + cc],                             \
                         m[r * 4 + 3] * SRC[12 + cc])));                        \
        }                                                                       \
    }
    CSTEP(qa, qb, 0); CSTEP(qb, qa, 1);
    CSTEP(qa, qb, 2); CSTEP(qb, qa, 3);
    CSTEP(qa, qb, 4); CSTEP(qb, qa, 5);
    CSTEP(qa, qb, 6);
#undef CSTEP

    #pragma unroll
    for (int i = 0; i < 16; ++i) q[t][i] = qb[i];
    __syncthreads();

    if (t < 64) {
        int b2 = blockIdx.x * 64 + t;
        const float2* Xp = (const float2*)X;
        float2 xv = Xp[(size_t)b2 * N_SITES];
        float inv = __builtin_amdgcn_rcpf(fmaf(xv.x, xv.x, xv.y * xv.y));
        float v0 = xv.x * xv.x * inv;
        float v1 = xv.y * xv.y * inv;
        float v2 = xv.x * xv.y * inv;
        float v3 = 0.f;
        #pragma unroll
        for (int jj = 0; jj < 4; ++jj) {
            const float* qq = q[jj * 64 + t];
            float n0 = fmaf(qq[0],  v0, fmaf(qq[1],  v1, fmaf(qq[2],  v2, qq[3]  * v3)));
            float n1 = fmaf(qq[4],  v0, fmaf(qq[5],  v1, fmaf(qq[6],  v2, qq[7]  * v3)));
            float n2 = fmaf(qq[8],  v0, fmaf(qq[9],  v1, fmaf(qq[10], v2, qq[11] * v3)));
            float n3 = fmaf(qq[12], v0, fmaf(qq[13], v1, fmaf(qq[14], v2, qq[15] * v3)));
            v0 = n0; v1 = n1; v2 = n2; v3 = n3;
        }
        out[b2] = v0;
    }
}

// ---------------------------------------------------------------------------
extern "C" void kernel_launch(void* const* d_in, const int* in_sizes, int n_in,
                              void* d_out, int out_size, void* d_ws, size_t ws_size,
                              hipStream_t stream) {
    const float* X  = (const float*)d_in[0];
    const float* kr = (const float*)d_in[1];
    const float* ki = (const float*)d_in[2];
    float* out = (float*)d_out;

    float* Tc = (float*)d_ws;
    const size_t Tb  = (size_t)L_PAD * 48 * sizeof(float);         // 150,528 (256-mult)
    const size_t XXb = (size_t)N_SITES * B_BATCH * sizeof(float2); // 51,380,224
    const size_t Pfb = (size_t)GF * 16 * B_BATCH * sizeof(float);  // 29,360,128

    build_T<<<L_PAD, 256, 0, stream>>>(kr, ki, Tc);

    if (ws_size >= Tb + XXb + Pfb) {
        // FAST path
        float2* XX = (float2*)((char*)d_ws + Tb);
        float*  P  = (float*)((char*)d_ws + Tb + XXb);

        dim3 gx(B_BATCH / 64, N_SITES / 16);
        xx_kernel<<<gx, 256, 0, stream>>>(X, XX);

        dim3 gs(B_BATCH / 256, GF);
        seg_fast<<<gs, 256, 0, stream>>>(XX, Tc, P);

        combine56<<<B_BATCH / 32, 256, 0, stream>>>(X, P, out);
    } else {
        // FALLBACK (round-4 path, 14.8 MB)
        float* P = (float*)((char*)d_ws + Tb);
        dim3 gs(B_BATCH / TPBS, GS);
        seg_slow<<<gs, TPBS, 0, stream>>>(X, Tc, P);
        combine28<<<B_BATCH / 64, 256, 0, stream>>>(X, P, out);
    }
}

// Round 7
// 38.485 us; speedup vs baseline: 3.3016x; 1.3490x over previous
//
#include <hip/hip_runtime.h>

#define L_LAYERS 783
#define L_PAD    784           // = SEGF*GF = SEGS*GS
#define B_BATCH  8192
#define N_SITES  784
#define K_KRAUS  16

// FAST path geometry
#define SEGF     14
#define GF       56
// FALLBACK geometry (round-4 path, proven within 15 MB workspace)
#define SEGS     28
#define GS       28
#define TPBS     128

// ---------------------------------------------------------------------------
// Hermitian-reduced formulation.
// State v = (s00, s11, u, w), sigma = [[s00, u+iw], [u-iw, s11]].
// Per layer: v' = R v, R = C + D*xx0 + B*xx1 (D = A - C, since xx0+xx3 = 1),
// xx = outer(x,x)/|x|^2. Tc per layer: 48 floats = [C(16) | D(16) | B(16)].
// Pad layers (l >= 783): R = I  (C=I, D=0, B=0).
// ---------------------------------------------------------------------------
__global__ void __launch_bounds__(256)
build_T(const float* __restrict__ kr, const float* __restrict__ ki,
        float* __restrict__ Tc) {
    __shared__ float lr[K_KRAUS * 16];
    __shared__ float li[K_KRAUS * 16];
    __shared__ float gr[48], gi[48];
    int l = blockIdx.x;
    int t = threadIdx.x;
    float* o = Tc + (size_t)l * 48;

    if (l >= L_LAYERS) {                        // identity pad layer
        if (t < 16) {
            int row = t >> 2, col = t & 3;
            o[t]      = (row == col) ? 1.f : 0.f;
            o[16 + t] = 0.f;
            o[32 + t] = 0.f;
        }
        return;
    }

    lr[t] = kr[(size_t)l * 256 + t];
    li[t] = ki[(size_t)l * 256 + t];
    __syncthreads();

    if (t < 192) {
        int e = t >> 2, chunk = t & 3;
        int ci = e >> 4;                        // 0,1,2
        int c = ci >> 1, d = (ci + 1) >> 1;     // (0,0),(0,1),(1,1)
        int m = (e >> 2) & 3, q = e & 3;
        int i1 = m >> 1, j1 = m & 1, i2 = q >> 1, j2 = q & 1;
        int off1 = c * 4 + 2 * i1 + i2;
        int off2 = d * 4 + 2 * j1 + j2;
        float ar = 0.f, ai = 0.f;
        #pragma unroll
        for (int kk = 0; kk < 4; ++kk) {
            int kbase = (chunk * 4 + kk) * 16;
            #pragma unroll
            for (int a = 0; a < 2; ++a) {
                int x1 = kbase + a * 8 + off1;
                int x2 = kbase + a * 8 + off2;
                float k1r = lr[x1], k1i = li[x1];
                float k2r = lr[x2], k2i = li[x2];
                ar += k1r * k2r + k1i * k2i;    // K1 * conj(K2)
                ai += k1i * k2r - k1r * k2i;
            }
        }
        ar += __shfl_xor(ar, 1); ar += __shfl_xor(ar, 2);
        ai += __shfl_xor(ai, 1); ai += __shfl_xor(ai, 2);
        if (chunk == 0) { gr[e] = ar; gi[e] = ai; }
    }
    __syncthreads();

    if (t < 16) {
        int row = t >> 2, col = t & 3;
        int ci = (row == 0) ? 0 : (row == 1) ? 2 : 1;
        int base = ci * 16;
        float Ur[4], Ui[4];
        #pragma unroll
        for (int q = 0; q < 4; ++q) {
            if (col == 0)      { Ur[q] = gr[base + q];      Ui[q] = gi[base + q]; }
            else if (col == 1) { Ur[q] = gr[base + 12 + q]; Ui[q] = gi[base + 12 + q]; }
            else {
                float t1r = gr[base + 4 + q], t1i = gi[base + 4 + q];
                float t2r = gr[base + 8 + q], t2i = gi[base + 8 + q];
                if (col == 2) { Ur[q] = t1r + t2r;    Ui[q] = t1i + t2i; }
                else          { Ur[q] = -(t1i - t2i); Ui[q] = t1r - t2r; }   // i*(T1-T2)
            }
        }
        float A, Bc, Cc;
        if (row == 3) { A = Ui[0]; Bc = Ui[1] + Ui[2]; Cc = Ui[3]; }
        else          { A = Ur[0]; Bc = Ur[1] + Ur[2]; Cc = Ur[3]; }
        o[t]      = Cc;
        o[16 + t] = A - Cc;
        o[32 + t] = Bc;
    }
}

// ---------------------------------------------------------------------------
// FAST kernel 2 (fused): per (batch-chunk, segment) product of SEGF transfer
// matrices. X staged through LDS with coalesced idx%SEGF mapping (no XX
// intermediate). LDS = 31.4 KB -> 5 blocks/CU; 256 thr -> ~20 waves/CU.
// P stored SoA: P[(s*16 + i) * B + b].
// ---------------------------------------------------------------------------
__global__ void __launch_bounds__(256, 4)
seg_fused(const float* __restrict__ X, const float* __restrict__ Tc,
          float* __restrict__ P) {
    __shared__ float4 tcs4[SEGF * 12];          // 2688 B
    __shared__ float2 xxs[256 * SEGF];          // 28672 B, [row][col] no pad
    int t  = threadIdx.x;
    int s  = blockIdx.y;
    int ls = s * SEGF;
    int b0 = blockIdx.x * 256;

    const float4* tg = (const float4*)Tc + (size_t)ls * 12;
    if (t < SEGF * 12) tcs4[t] = tg[t];         // 168 elems

    // coalesced stage: consecutive threads walk consecutive sites of one
    // batch row (112 B runs), rows advance every SEGF threads.
    const float2* Xp = (const float2*)X;
    #pragma unroll
    for (int e = 0; e < SEGF; ++e) {
        int idx  = t + e * 256;                 // 0..3583
        int row  = idx / SEGF;
        int col  = idx - row * SEGF;
        int site = ls + 1 + col;
        site = site < (N_SITES - 1) ? site : (N_SITES - 1);   // pad clamp
        float2 xv = Xp[(size_t)(b0 + row) * N_SITES + site];
        float inv = __builtin_amdgcn_rcpf(fmaf(xv.x, xv.x, xv.y * xv.y));
        xxs[row * SEGF + col] = make_float2(xv.x * xv.x * inv, xv.x * xv.y * inv);
    }
    __syncthreads();

    float pA[16], pB[16];
    #pragma unroll
    for (int i = 0; i < 16; ++i) pA[i] = (i % 5 == 0) ? 1.f : 0.f;

#define STEP(SRC, DST, I)                                                       \
    {                                                                           \
        float2 xx = xxs[t * SEGF + (I)];                                        \
        float R[16];                                                            \
        _Pragma("unroll")                                                       \
        for (int r = 0; r < 4; ++r) {                                           \
            float4 cv = tcs4[(I) * 12 + r];                                     \
            float4 dv = tcs4[(I) * 12 + 4 + r];                                 \
            float4 bv = tcs4[(I) * 12 + 8 + r];                                 \
            R[r * 4 + 0] = fmaf(bv.x, xx.y, fmaf(dv.x, xx.x, cv.x));            \
            R[r * 4 + 1] = fmaf(bv.y, xx.y, fmaf(dv.y, xx.x, cv.y));            \
            R[r * 4 + 2] = fmaf(bv.z, xx.y, fmaf(dv.z, xx.x, cv.z));            \
            R[r * 4 + 3] = fmaf(bv.w, xx.y, fmaf(dv.w, xx.x, cv.w));            \
        }                                                                       \
        _Pragma("unroll")                                                       \
        for (int r = 0; r < 4; ++r) {                                           \
            _Pragma("unroll")                                                   \
            for (int cc = 0; cc < 4; ++cc)                                      \
                DST[r * 4 + cc] =                                               \
                    fmaf(R[r * 4 + 0], SRC[cc],                                 \
                    fmaf(R[r * 4 + 1], SRC[4 + cc],                             \
                    fmaf(R[r * 4 + 2], SRC[8 + cc],                             \
                         R[r * 4 + 3] * SRC[12 + cc])));                        \
        }                                                                       \
    }

    #pragma unroll
    for (int i = 0; i < SEGF; i += 2) {         // SEGF even -> ends in pA
        STEP(pA, pB, i);
        STEP(pB, pA, i + 1);
    }
#undef STEP

    int b = b0 + t;
    #pragma unroll
    for (int i = 0; i < 16; ++i)
        P[((size_t)(s * 16 + i)) * B_BATCH + b] = pA[i];
}

// ---------------------------------------------------------------------------
// FAST kernel 3: two-level combine for G=56 (8 groups x 7-chain, then 8-chain).
// ---------------------------------------------------------------------------
__global__ void __launch_bounds__(256)
combine56(const float* __restrict__ X, const float* __restrict__ P,
          float* __restrict__ out) {
    __shared__ float q[256][17];
    int t = threadIdx.x;
    int j = t >> 5, bl = t & 31;
    int b = blockIdx.x * 32 + bl;

    float qa[16], qb[16];
    #pragma unroll
    for (int i = 0; i < 16; ++i) qa[i] = (i % 5 == 0) ? 1.f : 0.f;

#define CSTEP(SRC, DST, K)                                                      \
    {                                                                           \
        float m[16];                                                            \
        _Pragma("unroll")                                                       \
        for (int i = 0; i < 16; ++i)                                            \
            m[i] = P[((size_t)((j * 7 + (K)) * 16 + i)) * B_BATCH + b];         \
        _Pragma("unroll")                                                       \
        for (int r = 0; r < 4; ++r) {                                           \
            _Pragma("unroll")                                                   \
            for (int cc = 0; cc < 4; ++cc)                                      \
                DST[r * 4 + cc] =                                               \
                    fmaf(m[r * 4 + 0], SRC[cc],                                 \
                    fmaf(m[r * 4 + 1], SRC[4 + cc],                             \
                    fmaf(m[r * 4 + 2], SRC[8 + cc],                             \
                         m[r * 4 + 3] * SRC[12 + cc])));                        \
        }                                                                       \
    }
    CSTEP(qa, qb, 0); CSTEP(qb, qa, 1);
    CSTEP(qa, qb, 2); CSTEP(qb, qa, 3);
    CSTEP(qa, qb, 4); CSTEP(qb, qa, 5);
    CSTEP(qa, qb, 6);                          // result in qb
#undef CSTEP

    #pragma unroll
    for (int i = 0; i < 16; ++i) q[t][i] = qb[i];
    __syncthreads();

    if (t < 32) {
        int b2 = blockIdx.x * 32 + t;
        const float2* Xp = (const float2*)X;
        float2 xv = Xp[(size_t)b2 * N_SITES];
        float inv = __builtin_amdgcn_rcpf(fmaf(xv.x, xv.x, xv.y * xv.y));
        float v0 = xv.x * xv.x * inv;
        float v1 = xv.y * xv.y * inv;
        float v2 = xv.x * xv.y * inv;
        float v3 = 0.f;
        #pragma unroll
        for (int jj = 0; jj < 8; ++jj) {
            const float* qq = q[jj * 32 + t];
            float n0 = fmaf(qq[0],  v0, fmaf(qq[1],  v1, fmaf(qq[2],  v2, qq[3]  * v3)));
            float n1 = fmaf(qq[4],  v0, fmaf(qq[5],  v1, fmaf(qq[6],  v2, qq[7]  * v3)));
            float n2 = fmaf(qq[8],  v0, fmaf(qq[9],  v1, fmaf(qq[10], v2, qq[11] * v3)));
            float n3 = fmaf(qq[12], v0, fmaf(qq[13], v1, fmaf(qq[14], v2, qq[15] * v3)));
            v0 = n0; v1 = n1; v2 = n2; v3 = n3;
        }
        out[b2] = v0;
    }
}

// ---------------------------------------------------------------------------
// FALLBACK kernels (round-4 path, proven within 15 MB workspace)
// ---------------------------------------------------------------------------
__global__ void __launch_bounds__(TPBS)
seg_slow(const float* __restrict__ X, const float* __restrict__ Tc,
         float* __restrict__ P) {
    __shared__ float4 tcs4[SEGS * 12];
    __shared__ float2 xxs[TPBS][SEGS + 1];
    int t  = threadIdx.x;
    int s  = blockIdx.y;
    int ls = s * SEGS;
    int b0 = blockIdx.x * TPBS;

    const float4* tg = (const float4*)Tc + (size_t)ls * 12;
    #pragma unroll
    for (int i = t; i < SEGS * 12; i += TPBS) tcs4[i] = tg[i];

    const float2* Xp = (const float2*)X;
    for (int idx = t; idx < SEGS * TPBS; idx += TPBS) {
        int col  = idx % SEGS;
        int row  = idx / SEGS;
        int site = ls + 1 + col;
        site = site < (N_SITES - 1) ? site : (N_SITES - 1);
        float2 xv = Xp[(size_t)(b0 + row) * N_SITES + site];
        float inv = __builtin_amdgcn_rcpf(fmaf(xv.x, xv.x, xv.y * xv.y));
        xxs[row][col] = make_float2(xv.x * xv.x * inv, xv.x * xv.y * inv);
    }
    __syncthreads();

    float pA[16], pB[16];
    #pragma unroll
    for (int i = 0; i < 16; ++i) pA[i] = (i % 5 == 0) ? 1.f : 0.f;

#define STEP(SRC, DST, I)                                                       \
    {                                                                           \
        float2 xx = xxs[t][I];                                                  \
        float R[16];                                                            \
        _Pragma("unroll")                                                       \
        for (int r = 0; r < 4; ++r) {                                           \
            float4 cv = tcs4[(I) * 12 + r];                                     \
            float4 dv = tcs4[(I) * 12 + 4 + r];                                 \
            float4 bv = tcs4[(I) * 12 + 8 + r];                                 \
            R[r * 4 + 0] = fmaf(bv.x, xx.y, fmaf(dv.x, xx.x, cv.x));            \
            R[r * 4 + 1] = fmaf(bv.y, xx.y, fmaf(dv.y, xx.x, cv.y));            \
            R[r * 4 + 2] = fmaf(bv.z, xx.y, fmaf(dv.z, xx.x, cv.z));            \
            R[r * 4 + 3] = fmaf(bv.w, xx.y, fmaf(dv.w, xx.x, cv.w));            \
        }                                                                       \
        _Pragma("unroll")                                                       \
        for (int r = 0; r < 4; ++r) {                                           \
            _Pragma("unroll")                                                   \
            for (int cc = 0; cc < 4; ++cc)                                      \
                DST[r * 4 + cc] =                                               \
                    fmaf(R[r * 4 + 0], SRC[cc],                                 \
                    fmaf(R[r * 4 + 1], SRC[4 + cc],                             \
                    fmaf(R[r * 4 + 2], SRC[8 + cc],                             \
                         R[r * 4 + 3] * SRC[12 + cc])));                        \
        }                                                                       \
    }

    #pragma unroll
    for (int i = 0; i < SEGS; i += 2) {
        STEP(pA, pB, i);
        STEP(pB, pA, i + 1);
    }
#undef STEP

    int b = b0 + t;
    #pragma unroll
    for (int i = 0; i < 16; ++i)
        P[((size_t)(s * 16 + i)) * B_BATCH + b] = pA[i];
}

__global__ void __launch_bounds__(256)
combine28(const float* __restrict__ X, const float* __restrict__ P,
          float* __restrict__ out) {
    __shared__ float q[256][17];
    int t  = threadIdx.x;
    int j  = t >> 6;
    int bl = t & 63;
    int b  = blockIdx.x * 64 + bl;

    float qa[16], qb[16];
    #pragma unroll
    for (int i = 0; i < 16; ++i) qa[i] = (i % 5 == 0) ? 1.f : 0.f;

#define CSTEP(SRC, DST, K)                                                      \
    {                                                                           \
        float m[16];                                                            \
        _Pragma("unroll")                                                       \
        for (int i = 0; i < 16; ++i)                                            \
            m[i] = P[((size_t)((j * 7 + (K)) * 16 + i)) * B_BATCH + b];         \
        _Pragma("unroll")                                                       \
        for (int r = 0; r < 4; ++r) {                                           \
            _Pragma("unroll")                                                   \
            for (int cc = 0; cc < 4; ++cc)                                      \
                DST[r * 4 + cc] =                                               \
                    fmaf(m[r * 4 + 0], SRC[cc],                                 \
                    fmaf(m[r * 4 + 1], SRC[4 + cc],                             \
                    fmaf(m[r * 4 + 2], SRC[8 + cc],                             \
                         m[r * 4 + 3] * SRC[12 + cc])));                        \
        }                                                                       \
    }
    CSTEP(qa, qb, 0); CSTEP(qb, qa, 1);
    CSTEP(qa, qb, 2); CSTEP(qb, qa, 3);
    CSTEP(qa, qb, 4); CSTEP(qb, qa, 5);
    CSTEP(qa, qb, 6);
#undef CSTEP

    #pragma unroll
    for (int i = 0; i < 16; ++i) q[t][i] = qb[i];
    __syncthreads();

    if (t < 64) {
        int b2 = blockIdx.x * 64 + t;
        const float2* Xp = (const float2*)X;
        float2 xv = Xp[(size_t)b2 * N_SITES];
        float inv = __builtin_amdgcn_rcpf(fmaf(xv.x, xv.x, xv.y * xv.y));
        float v0 = xv.x * xv.x * inv;
        float v1 = xv.y * xv.y * inv;
        float v2 = xv.x * xv.y * inv;
        float v3 = 0.f;
        #pragma unroll
        for (int jj = 0; jj < 4; ++jj) {
            const float* qq = q[jj * 64 + t];
            float n0 = fmaf(qq[0],  v0, fmaf(qq[1],  v1, fmaf(qq[2],  v2, qq[3]  * v3)));
            float n1 = fmaf(qq[4],  v0, fmaf(qq[5],  v1, fmaf(qq[6],  v2, qq[7]  * v3)));
            float n2 = fmaf(qq[8],  v0, fmaf(qq[9],  v1, fmaf(qq[10], v2, qq[11] * v3)));
            float n3 = fmaf(qq[12], v0, fmaf(qq[13], v1, fmaf(qq[14], v2, qq[15] * v3)));
            v0 = n0; v1 = n1; v2 = n2; v3 = n3;
        }
        out[b2] = v0;
    }
}

// ---------------------------------------------------------------------------
extern "C" void kernel_launch(void* const* d_in, const int* in_sizes, int n_in,
                              void* d_out, int out_size, void* d_ws, size_t ws_size,
                              hipStream_t stream) {
    const float* X  = (const float*)d_in[0];
    const float* kr = (const float*)d_in[1];
    const float* ki = (const float*)d_in[2];
    float* out = (float*)d_out;

    float* Tc = (float*)d_ws;
    const size_t Tb  = (size_t)L_PAD * 48 * sizeof(float);         // 150,528 (256-mult)
    const size_t Pfb = (size_t)GF * 16 * B_BATCH * sizeof(float);  // 29,360,128

    build_T<<<L_PAD, 256, 0, stream>>>(kr, ki, Tc);

    if (ws_size >= Tb + Pfb) {
        // FAST path: fused stage+product, no XX intermediate
        float* P = (float*)((char*)d_ws + Tb);
        dim3 gs(B_BATCH / 256, GF);
        seg_fused<<<gs, 256, 0, stream>>>(X, Tc, P);
        combine56<<<B_BATCH / 32, 256, 0, stream>>>(X, P, out);
    } else {
        // FALLBACK (round-4 path, 14.8 MB)
        float* P = (float*)((char*)d_ws + Tb);
        dim3 gs(B_BATCH / TPBS, GS);
        seg_slow<<<gs, TPBS, 0, stream>>>(X, Tc, P);
        combine28<<<B_BATCH / 64, 256, 0, stream>>>(X, P, out);
    }
}